// Round 12
// baseline (241.414 us; speedup 1.0000x reference)
//
#include <hip/hip_runtime.h>
#include <hip/hip_bf16.h>

// EventSequenceEncoder: embed -> QKV gemm -> attention -> Wout(+res) -> LN ->
// FF1(relu) -> FF2(+res) -> LN -> mean-pool.  attn_tokens == 1/L analytically.
// R12: QKV GEMM moved to BM=256xBN=256 (per-wave 128x64): 30% less LDS traffic
// per FLOP, 2x fewer barriers+stage-loads per FLOP. 2-subphase skeleton kept.
// Small GEMMs stay on the 128x256 template.  Rest identical to R11 (230us).

#define Dm 1024
#define Hh 16
#define Bb 8
#define Ll 1024
#define Mm 8192
#define LNEPS 1e-5f
#define QSCALE 0.18033688f   // 0.125 * log2(e)

typedef __attribute__((ext_vector_type(8))) short s16x8;
typedef __attribute__((ext_vector_type(4))) short s16x4;
typedef __attribute__((ext_vector_type(4))) float f32x4;

using bf16 = __hip_bfloat16;

__device__ __forceinline__ short f2bs(float f) {
  return __builtin_bit_cast(short, __float2bfloat16(f));
}
__device__ __forceinline__ float b2f(short s) {
  return __builtin_bit_cast(float, ((unsigned)(unsigned short)s) << 16);
}

__device__ __forceinline__ unsigned cvtpk(float lo, float hi) {
  unsigned r;
  asm("v_cvt_pk_bf16_f32 %0, %1, %2" : "=v"(r) : "v"(lo), "v"(hi));
  return r;
}

__device__ __forceinline__ void gload16(const void* g, void* l) {
  __builtin_amdgcn_global_load_lds(
      (__attribute__((address_space(1))) void*)g,
      (__attribute__((address_space(3))) void*)l, 16, 0, 0);
}

// ------ prep: 4 weight f32->bf16 casts (Q-rows pre-scaled) + fused embedding -
__global__ __launch_bounds__(256) void k_prep(
    const float* __restrict__ w0, const float* __restrict__ w1,
    const float* __restrict__ w2, const float* __restrict__ w3,
    bf16* __restrict__ o0, bf16* __restrict__ o1,
    bf16* __restrict__ o2, bf16* __restrict__ o3,
    const int* __restrict__ tids, const float* __restrict__ vals,
    const float* __restrict__ dels, const float* __restrict__ temb,
    const float* __restrict__ Wv, const float* __restrict__ bv,
    const float* __restrict__ Wt, const float* __restrict__ bt,
    bf16* __restrict__ hb)
{
  const int bId = blockIdx.x;
  if (bId < 6144) {
    const float* src; bf16* dst; int rel;
    float sc = 1.f;
    if (bId < 3072)      { src = w0; dst = o0; rel = bId; if (bId < 1024) sc = QSCALE; }
    else if (bId < 4096) { src = w1; dst = o1; rel = bId - 3072; }
    else if (bId < 5120) { src = w2; dst = o2; rel = bId - 4096; }
    else                 { src = w3; dst = o3; rel = bId - 5120; }
    const size_t i = ((size_t)rel * 256 + threadIdx.x) * 4;
    const float4 v = *(const float4*)&src[i];
    s16x4 o;
    o[0] = f2bs(v.x * sc); o[1] = f2bs(v.y * sc); o[2] = f2bs(v.z * sc); o[3] = f2bs(v.w * sc);
    *(s16x4*)&dst[i] = o;
  } else {
    const int row = bId - 6144;
    const int ty = tids[row];
    const float v = vals[row], dl = dels[row];
    const int d0 = threadIdx.x * 4;
    const float4 e  = *(const float4*)&temb[(size_t)ty * Dm + d0];
    const float4 wv = *(const float4*)&Wv[d0];
    const float4 c1 = *(const float4*)&bv[d0];
    const float4 wt = *(const float4*)&Wt[d0];
    const float4 c2 = *(const float4*)&bt[d0];
    s16x4 o;
    o[0] = f2bs(e.x + v * wv.x + c1.x + dl * wt.x + c2.x);
    o[1] = f2bs(e.y + v * wv.y + c1.y + dl * wt.y + c2.y);
    o[2] = f2bs(e.z + v * wv.z + c1.z + dl * wt.z + c2.z);
    o[3] = f2bs(e.w + v * wv.w + c1.w + dl * wt.w + c2.w);
    *(s16x4*)((short*)hb + (size_t)row * Dm + d0) = o;
  }
}

// -------- QKV GEMM: BM=256, BN=256, BK=64, 8 waves (2Mx4N), wave = 128x64 ----
// LDS 128KB: 2 bufs x (A[256][64] + B[256][64]) bf16, XOR-swizzle slot^(row&7).
// SP0{rd fa(8)+fb(4) @k0 | stage A(t+1)[4]} -> 32 MFMA
// SP1{rd fa(8)+fb(4) @k1 | stage B(t+1)[4]} -> 32 MFMA
// boundary vmcnt(0) (only t+1's 8 loads outstanding; 1-phase covered).
// Epilogue: Q-bias scale (cols<1024) + V redirect (cols>=2048 -> vt layout).
__global__ __launch_bounds__(512) void k_gemmQ(
    const bf16* __restrict__ A, const bf16* __restrict__ Bt,
    const float* __restrict__ bias,
    bf16* __restrict__ outB, bf16* __restrict__ vt, const int N, const int K)
{
  __shared__ __attribute__((aligned(16))) short lds[65536];  // 128KB
  const int tid = threadIdx.x, lane = tid & 63, wave = tid >> 6;
  const int wr = wave >> 2, wc = wave & 3;
  const int l15 = lane & 15, lg = (lane >> 4) & 3;
  const int bm = blockIdx.x, bn = blockIdx.y;
  const int NT = K >> 6;

  const int rl = tid >> 3;                 // 0..63
  const int swz = ((tid & 7) ^ (rl & 7)) * 8;
  const bf16* aSrc = A  + (size_t)(bm * 256 + rl) * K + swz;
  const bf16* bSrc = Bt + (size_t)(bn * 256 + rl) * K + swz;

  f32x4 acc[8][4] = {};

  auto stageA = [&](int t) {               // 4 gloads: 256 rows
    const int base = (t & 1) * 32768;
    gload16(aSrc + t * 64,                    &lds[base         + tid * 8]);
    gload16(aSrc + (size_t) 64 * K + t * 64,  &lds[base +  4096 + tid * 8]);
    gload16(aSrc + (size_t)128 * K + t * 64,  &lds[base +  8192 + tid * 8]);
    gload16(aSrc + (size_t)192 * K + t * 64,  &lds[base + 12288 + tid * 8]);
  };
  auto stageB = [&](int t) {
    const int base = (t & 1) * 32768 + 16384;
    gload16(bSrc + t * 64,                    &lds[base         + tid * 8]);
    gload16(bSrc + (size_t) 64 * K + t * 64,  &lds[base +  4096 + tid * 8]);
    gload16(bSrc + (size_t)128 * K + t * 64,  &lds[base +  8192 + tid * 8]);
    gload16(bSrc + (size_t)192 * K + t * 64,  &lds[base + 12288 + tid * 8]);
  };

  // prologue: tile 0
  stageA(0); stageB(0);
  asm volatile("s_waitcnt vmcnt(0)" ::: "memory");
  __builtin_amdgcn_sched_barrier(0);
  __builtin_amdgcn_s_barrier();

  for (int t = 0; t < NT; ++t) {
    const int cb = (t & 1) * 32768;
    s16x8 fa[8], fb[4];

    // ---- SP0 (k-step 0): read 8 fa + 4 fb; stage A(t+1)
#pragma unroll
    for (int m = 0; m < 8; ++m) {
      const int row = wr * 128 + m * 16 + l15;
      fa[m] = *(const s16x8*)&lds[cb + row * 64 + ((lg ^ (row & 7)) << 3)];
    }
#pragma unroll
    for (int n = 0; n < 4; ++n) {
      const int row = wc * 64 + n * 16 + l15;
      fb[n] = *(const s16x8*)&lds[cb + 16384 + row * 64 + ((lg ^ (row & 7)) << 3)];
    }
    if (t + 1 < NT) stageA(t + 1);
    __builtin_amdgcn_s_barrier();
    asm volatile("s_waitcnt lgkmcnt(0)" ::: "memory");
    __builtin_amdgcn_sched_barrier(0);
    __builtin_amdgcn_s_setprio(1);
#pragma unroll
    for (int m = 0; m < 8; ++m)
#pragma unroll
      for (int n = 0; n < 4; ++n)
        acc[m][n] = __builtin_amdgcn_mfma_f32_16x16x32_bf16(fa[m], fb[n], acc[m][n], 0, 0, 0);
    __builtin_amdgcn_s_setprio(0);
    __builtin_amdgcn_s_barrier();

    // ---- SP1 (k-step 1): read 8 fa + 4 fb; stage B(t+1)
#pragma unroll
    for (int m = 0; m < 8; ++m) {
      const int row = wr * 128 + m * 16 + l15;
      fa[m] = *(const s16x8*)&lds[cb + row * 64 + (((4 + lg) ^ (row & 7)) << 3)];
    }
#pragma unroll
    for (int n = 0; n < 4; ++n) {
      const int row = wc * 64 + n * 16 + l15;
      fb[n] = *(const s16x8*)&lds[cb + 16384 + row * 64 + (((4 + lg) ^ (row & 7)) << 3)];
    }
    if (t + 1 < NT) stageB(t + 1);
    __builtin_amdgcn_s_barrier();
    asm volatile("s_waitcnt lgkmcnt(0)" ::: "memory");
    __builtin_amdgcn_sched_barrier(0);
    __builtin_amdgcn_s_setprio(1);
#pragma unroll
    for (int m = 0; m < 8; ++m)
#pragma unroll
      for (int n = 0; n < 4; ++n)
        acc[m][n] = __builtin_amdgcn_mfma_f32_16x16x32_bf16(fa[m], fb[n], acc[m][n], 0, 0, 0);
    __builtin_amdgcn_s_setprio(0);

    // ---- boundary: tile t+1's 8 loads (issued SP0/SP1) must land
    if (t + 1 < NT) {
      asm volatile("s_waitcnt vmcnt(0)" ::: "memory");
      __builtin_amdgcn_sched_barrier(0);
      __builtin_amdgcn_s_barrier();
    }
  }

  // epilogue: Q-bias scale + V redirect
#pragma unroll
  for (int n = 0; n < 4; ++n) {
    const int col = bn * 256 + wc * 64 + n * 16 + l15;
    float bc = bias[col];
    if (col < 1024) bc *= QSCALE;
    if (col >= 2048) {
      const int hh = (col - 2048) >> 6, dh = (col - 2048) & 63;
#pragma unroll
      for (int m = 0; m < 8; ++m) {
        const size_t row0 = (size_t)bm * 256 + wr * 128 + m * 16 + lg * 4;
        const int bb = (int)(row0 >> 10), l0 = (int)(row0 & 1023);
        s16x4 pk;
#pragma unroll
        for (int i = 0; i < 4; ++i) pk[i] = f2bs(acc[m][n][i] + bc);
        *(s16x4*)((short*)vt + ((size_t)((bb * 16 + hh) * 64 + dh)) * Ll + l0) = pk;
      }
    } else {
#pragma unroll
      for (int m = 0; m < 8; ++m) {
#pragma unroll
        for (int i = 0; i < 4; ++i) {
          const size_t row = (size_t)bm * 256 + wr * 128 + m * 16 + lg * 4 + i;
          outB[row * N + col] = __float2bfloat16(acc[m][n][i] + bc);
        }
      }
    }
  }
}

// ---------------- 2-subphase GEMM (R3): out = A @ Bt^T + bias (+bf16 res) ---
template<bool RELU, bool RES>
__global__ __launch_bounds__(512) void k_gemm8(
    const bf16* __restrict__ A, const bf16* __restrict__ Bt,
    const float* __restrict__ bias, const bf16* __restrict__ res,
    bf16* __restrict__ outB, const int N, const int K)
{
  __shared__ __attribute__((aligned(16))) short lds[49152];  // 2 x (8192 A + 16384 B)
  const int tid = threadIdx.x, lane = tid & 63, wave = tid >> 6;
  const int wr = wave >> 2, wc = wave & 3;
  const int l15 = lane & 15, lg = (lane >> 4) & 3;
  const int bm = blockIdx.x, bn = blockIdx.y;
  const int NT = K >> 6;

  const int rl = tid >> 3;
  const int swz = ((tid & 7) ^ (rl & 7)) * 8;
  const bf16* aSrc = A  + (size_t)(bm * 128 + rl) * K + swz;
  const bf16* bSrc = Bt + (size_t)(bn * 256 + rl) * K + swz;

  f32x4 acc[4][4] = {};

  auto stageA = [&](int t, int h) {
    gload16(aSrc + (size_t)h * 64 * K + t * 64,
            &lds[(t & 1) * 24576 + h * 4096 + tid * 8]);
  };
  auto stageB = [&](int t, int h) {
    gload16(bSrc + (size_t)h * 128 * K + t * 64,
            &lds[(t & 1) * 24576 + 8192 + h * 8192 + tid * 8]);
    gload16(bSrc + (size_t)(h * 128 + 64) * K + t * 64,
            &lds[(t & 1) * 24576 + 8192 + h * 8192 + 4096 + tid * 8]);
  };

  stageA(0, 0); stageA(0, 1); stageB(0, 0); stageB(0, 1);
  if (NT > 1) { stageA(1, 0); stageA(1, 1); }
  asm volatile("s_waitcnt vmcnt(2)" ::: "memory");
  __builtin_amdgcn_sched_barrier(0);
  __builtin_amdgcn_s_barrier();

  for (int t = 0; t < NT; ++t) {
    const int cb = (t & 1) * 24576;
    s16x8 fa[4][2], fb[2][2];

#pragma unroll
    for (int m = 0; m < 4; ++m)
#pragma unroll
      for (int ks = 0; ks < 2; ++ks) {
        const int row = wr * 64 + m * 16 + l15;
        fa[m][ks] = *(const s16x8*)&lds[cb + row * 64 + (((ks * 4 + lg) ^ (row & 7)) << 3)];
      }
#pragma unroll
    for (int n = 0; n < 2; ++n)
#pragma unroll
      for (int ks = 0; ks < 2; ++ks) {
        const int row = wc * 64 + n * 16 + l15;
        fb[n][ks] = *(const s16x8*)&lds[cb + 8192 + row * 64 + (((ks * 4 + lg) ^ (row & 7)) << 3)];
      }
    if (t + 1 < NT) { stageB(t + 1, 0); stageB(t + 1, 1); }
    __builtin_amdgcn_s_barrier();
    asm volatile("s_waitcnt lgkmcnt(0)" ::: "memory");
    __builtin_amdgcn_sched_barrier(0);
    __builtin_amdgcn_s_setprio(1);
#pragma unroll
    for (int m = 0; m < 4; ++m)
#pragma unroll
      for (int n = 0; n < 2; ++n)
#pragma unroll
        for (int ks = 0; ks < 2; ++ks)
          acc[m][n] = __builtin_amdgcn_mfma_f32_16x16x32_bf16(fa[m][ks], fb[n][ks], acc[m][n], 0, 0, 0);
    __builtin_amdgcn_s_setprio(0);
    __builtin_amdgcn_s_barrier();

#pragma unroll
    for (int n = 0; n < 2; ++n)
#pragma unroll
      for (int ks = 0; ks < 2; ++ks) {
        const int row = wc * 64 + (2 + n) * 16 + l15;
        fb[n][ks] = *(const s16x8*)&lds[cb + 8192 + row * 64 + (((ks * 4 + lg) ^ (row & 7)) << 3)];
      }
    if (t + 2 < NT) { stageA(t + 2, 0); stageA(t + 2, 1); }
    __builtin_amdgcn_s_barrier();
    asm volatile("s_waitcnt lgkmcnt(0)" ::: "memory");
    __builtin_amdgcn_sched_barrier(0);
    __builtin_amdgcn_s_setprio(1);
#pragma unroll
    for (int m = 0; m < 4; ++m)
#pragma unroll
      for (int n = 0; n < 2; ++n)
#pragma unroll
        for (int ks = 0; ks < 2; ++ks)
          acc[m][2 + n] = __builtin_amdgcn_mfma_f32_16x16x32_bf16(fa[m][ks], fb[n][ks], acc[m][2 + n], 0, 0, 0);
    __builtin_amdgcn_s_setprio(0);

    if (t + 1 < NT) {
      if (t + 2 < NT) asm volatile("s_waitcnt vmcnt(2)" ::: "memory");
      else            asm volatile("s_waitcnt vmcnt(0)" ::: "memory");
      __builtin_amdgcn_sched_barrier(0);
      __builtin_amdgcn_s_barrier();
    }
  }

#pragma unroll
  for (int n = 0; n < 4; ++n) {
    const int col = bn * 256 + wc * 64 + n * 16 + l15;
    const float bc = bias[col];
#pragma unroll
    for (int m = 0; m < 4; ++m) {
#pragma unroll
      for (int i = 0; i < 4; ++i) {
        const size_t row = (size_t)bm * 128 + wr * 64 + m * 16 + lg * 4 + i;
        float v = acc[m][n][i] + bc;
        if constexpr (RES)  v += b2f(((const short*)res)[row * N + col]);
        if constexpr (RELU) v = fmaxf(v, 0.f);
        outB[row * N + col] = __float2bfloat16(v);
      }
    }
  }
}

// ---------------- attention (R5): swapped QK^T, wave-private P, QBLK=128 -----
__global__ __launch_bounds__(256) void k_attn(
    const bf16* __restrict__ qkv, const bf16* __restrict__ vt, bf16* __restrict__ attnb)
{
  const int bh = blockIdx.x;
  const int qb = blockIdx.y;
  const int b = bh >> 4, h = bh & 15;
  __shared__ __attribute__((aligned(16))) short lK[8192];   // 2 x [64][64] swz
  __shared__ __attribute__((aligned(16))) short lV[8192];   // 2 x [64][64] swz
  __shared__ __attribute__((aligned(16))) short lP[8192];   // [128][64] swz, wave-private rows
  const int tid = threadIdx.x, lane = tid & 63, wave = tid >> 6;
  const int l15 = lane & 15, lg = lane >> 4;
  const int qrow = wave * 32;
  const int l7 = l15 & 7;

  s16x8 qf[2][2];
#pragma unroll
  for (int mq = 0; mq < 2; ++mq)
#pragma unroll
    for (int ks = 0; ks < 2; ++ks)
      qf[mq][ks] = *(const s16x8*)((const short*)qkv +
          ((size_t)(b * Ll + qb * 128 + qrow + mq * 16 + l15)) * 3072 + h * 64 + ks * 32 + lg * 8);

  f32x4 o[2][4] = {};
  float rs[2] = {0.f, 0.f};

  const int sr = tid >> 3;
  const int swz = (tid & 7) ^ (sr & 7);

  auto stage = [&](int mc) {
    const int bo = (mc & 1) * 4096;
    const bf16* gk = qkv + ((size_t)(b * Ll + mc * 64 + sr)) * 3072 + 1024 + h * 64 + swz * 8;
    gload16(gk,                     &lK[bo + tid * 8]);
    gload16(gk + (size_t)32 * 3072, &lK[bo + 2048 + tid * 8]);
    const bf16* gv = vt + ((size_t)(bh * 64 + sr)) * Ll + mc * 64 + swz * 8;
    gload16(gv,                   &lV[bo + tid * 8]);
    gload16(gv + (size_t)32 * Ll, &lV[bo + 2048 + tid * 8]);
  };

  stage(0);

  for (int mc = 0; mc < 16; ++mc) {
    asm volatile("s_waitcnt vmcnt(0)" ::: "memory");
    __builtin_amdgcn_s_barrier();
    __builtin_amdgcn_sched_barrier(0);
    if (mc + 1 < 16) stage(mc + 1);
    const int bo = (mc & 1) * 4096;

    f32x4 st[2][4] = {};
    __builtin_amdgcn_s_setprio(1);
#pragma unroll
    for (int ks = 0; ks < 2; ++ks) {
#pragma unroll
      for (int n = 0; n < 4; ++n) {
        const int kr = n * 16 + l15;
        const s16x8 kf = *(const s16x8*)&lK[bo + kr * 64 + (((ks * 4 + lg) ^ l7) << 3)];
        st[0][n] = __builtin_amdgcn_mfma_f32_16x16x32_bf16(kf, qf[0][ks], st[0][n], 0, 0, 0);
        st[1][n] = __builtin_amdgcn_mfma_f32_16x16x32_bf16(kf, qf[1][ks], st[1][n], 0, 0, 0);
      }
    }
    __builtin_amdgcn_s_setprio(0);

#pragma unroll
    for (int mq = 0; mq < 2; ++mq) {
      const int qr = qrow + mq * 16 + l15;
      short* prow = &lP[qr * 64];
      float loc = 0.f;
#pragma unroll
      for (int n = 0; n < 4; ++n) {
        const float e0 = __builtin_amdgcn_exp2f(st[mq][n][0]);
        const float e1 = __builtin_amdgcn_exp2f(st[mq][n][1]);
        const float e2 = __builtin_amdgcn_exp2f(st[mq][n][2]);
        const float e3 = __builtin_amdgcn_exp2f(st[mq][n][3]);
        loc += (e0 + e1) + (e2 + e3);
        const unsigned c0 = cvtpk(e0, e1);
        const unsigned c1 = cvtpk(e2, e3);
        const int col0 = n * 16 + lg * 4;
        const int scol = ((((col0 >> 3) ^ (qr & 7)) << 3) | (col0 & 7));
        *(unsigned*)&prow[scol]     = c0;
        *(unsigned*)&prow[scol + 2] = c1;
      }
      rs[mq] += loc;
    }

    __builtin_amdgcn_s_setprio(1);
#pragma unroll
    for (int ks = 0; ks < 2; ++ks) {
      s16x8 pa[2];
#pragma unroll
      for (int mq = 0; mq < 2; ++mq) {
        const int qr = qrow + mq * 16 + l15;
        pa[mq] = *(const s16x8*)&lP[qr * 64 + (((ks * 4 + lg) ^ (qr & 7)) << 3)];
      }
#pragma unroll
      for (int dn = 0; dn < 4; ++dn) {
        const int vr = dn * 16 + l15;
        const s16x8 vf = *(const s16x8*)&lV[bo + vr * 64 + (((ks * 4 + lg) ^ l7) << 3)];
        o[0][dn] = __builtin_amdgcn_mfma_f32_16x16x32_bf16(pa[0], vf, o[0][dn], 0, 0, 0);
        o[1][dn] = __builtin_amdgcn_mfma_f32_16x16x32_bf16(pa[1], vf, o[1][dn], 0, 0, 0);
      }
    }
    __builtin_amdgcn_s_setprio(0);
    asm volatile("s_waitcnt lgkmcnt(0)" ::: "memory");
  }

#pragma unroll
  for (int mq = 0; mq < 2; ++mq) {
    rs[mq] += __shfl_xor(rs[mq], 16);
    rs[mq] += __shfl_xor(rs[mq], 32);
  }
#pragma unroll
  for (int mq = 0; mq < 2; ++mq) {
    float inv[4];
#pragma unroll
    for (int i = 0; i < 4; ++i)
      inv[i] = 1.f / __shfl(rs[mq], lg * 4 + i);
#pragma unroll
    for (int dn = 0; dn < 4; ++dn) {
#pragma unroll
      for (int i = 0; i < 4; ++i) {
        const int q = qb * 128 + qrow + mq * 16 + lg * 4 + i;
        attnb[((size_t)(b * Ll + q)) * Dm + h * 64 + dn * 16 + l15] =
            __float2bfloat16(o[mq][dn][i] * inv[i]);
      }
    }
  }
}

// ---------------- LayerNorm: bf16 in, bf16 out (one row per block) ----------
__global__ __launch_bounds__(256) void k_ln(const bf16* __restrict__ x,
    const float* __restrict__ gamma, const float* __restrict__ beta,
    bf16* __restrict__ y)
{
  const size_t row = blockIdx.x;
  const int d0 = threadIdx.x * 4;
  const s16x4 xv = *(const s16x4*)((const short*)x + row * Dm + d0);
  float f0 = b2f(xv[0]), f1 = b2f(xv[1]), f2 = b2f(xv[2]), f3 = b2f(xv[3]);
  float s  = (f0 + f1) + (f2 + f3);
  float ss = (f0 * f0 + f1 * f1) + (f2 * f2 + f3 * f3);
#pragma unroll
  for (int m = 1; m < 64; m <<= 1) { s += __shfl_xor(s, m); ss += __shfl_xor(ss, m); }
  __shared__ float red[8];
  const int wv = threadIdx.x >> 6;
  if ((threadIdx.x & 63) == 0) { red[wv] = s; red[4 + wv] = ss; }
  __syncthreads();
  s  = red[0] + red[1] + red[2] + red[3];
  ss = red[4] + red[5] + red[6] + red[7];
  const float mu = s * (1.f / Dm);
  const float rstd = rsqrtf(ss * (1.f / Dm) - mu * mu + LNEPS);
  const float4 g  = *(const float4*)&gamma[d0];
  const float4 be = *(const float4*)&beta[d0];
  s16x4 o;
  o[0] = f2bs((f0 - mu) * rstd * g.x + be.x);
  o[1] = f2bs((f1 - mu) * rstd * g.y + be.y);
  o[2] = f2bs((f2 - mu) * rstd * g.z + be.z);
  o[3] = f2bs((f3 - mu) * rstd * g.w + be.w);
  *(s16x4*)((short*)y + row * Dm + d0) = o;
}

// ---------------- mean pool (bf16 in) ----------------
__global__ __launch_bounds__(256) void k_pool_part(const bf16* __restrict__ h3, float* __restrict__ part)
{
  const int b = blockIdx.x, lcn = blockIdx.y, dz = blockIdx.z;
  const int d = dz * 256 + threadIdx.x;
  float s = 0.f;
#pragma unroll 4
  for (int l = 0; l < 64; ++l)
    s += b2f(((const short*)h3)[((size_t)(b * Ll + lcn * 64 + l)) * Dm + d]);
  part[((size_t)(b * 16 + lcn)) * Dm + d] = s;
}

__global__ __launch_bounds__(256) void k_pool_fin(const float* __restrict__ part, float* __restrict__ out)
{
  const int b = blockIdx.x;
  const int d = blockIdx.y * 256 + threadIdx.x;
  float s = 0.f;
#pragma unroll
  for (int c = 0; c < 16; ++c) s += part[((size_t)(b * 16 + c)) * Dm + d];
  out[b * Dm + d] = s * (1.f / Ll);
  out[(size_t)Mm + b * Dm + d] = 1.f / Ll;  // attn_tokens == 1/L analytically
}

extern "C" void kernel_launch(void* const* d_in, const int* in_sizes, int n_in,
                              void* d_out, int out_size, void* d_ws, size_t ws_size,
                              hipStream_t stream) {
  const int*   tids  = (const int*)  d_in[0];
  const float* vals  = (const float*)d_in[1];
  const float* dels  = (const float*)d_in[2];
  const float* temb  = (const float*)d_in[3];
  const float* Wv    = (const float*)d_in[4];
  const float* bv    = (const float*)d_in[5];
  const float* Wt    = (const float*)d_in[6];
  const float* bt    = (const float*)d_in[7];
  const float* Win   = (const float*)d_in[8];
  const float* bin   = (const float*)d_in[9];
  const float* Wout  = (const float*)d_in[10];
  const float* bout  = (const float*)d_in[11];
  const float* W1    = (const float*)d_in[12];
  const float* b1    = (const float*)d_in[13];
  const float* W2    = (const float*)d_in[14];
  const float* b2    = (const float*)d_in[15];
  const float* gamma = (const float*)d_in[16];
  const float* beta  = (const float*)d_in[17];
  float* out = (float*)d_out;

  char* w = (char*)d_ws;
  const size_t MB = 1ull << 20;
  bf16*  hb    = (bf16*) (w + 0);         // [0,16)    h bf16 (QKV-A, Wout-res)
  bf16*  qkv   = (bf16*) (w + 16 * MB);   // [16,64)   q,k bf16 (V redirected)
  bf16*  vtb   = (bf16*) (w + 64 * MB);   // [64,80)   v^T (written by QKV gemm)
  bf16*  attnb = (bf16*) (w + 80 * MB);   // [80,96)   attn out (dead after Wout)
  bf16*  x1b   = (bf16*) (w + 16 * MB);   // [16,32)   h+attnout (qkv dead)
  bf16*  h2b   = (bf16*) (w + 32 * MB);   // [32,48)   LN1 out (FF1-A, FF2-res)
  bf16*  ff1   = (bf16*) (w + 48 * MB);   // [48,64)   relu(ff1)
  bf16*  x2b   = (bf16*) (w + 64 * MB);   // [64,80)   h2+ff2 (vtb dead)
  bf16*  h3b   = (bf16*) (w + 80 * MB);   // [80,96)   LN2 out (attnb dead)
  bf16*  WinB  = (bf16*) (w + 96 * MB);
  bf16*  WoutB = (bf16*) (w + 102 * MB);
  bf16*  W1B   = (bf16*) (w + 104 * MB);
  bf16*  W2B   = (bf16*) (w + 106 * MB);
  float* part  = (float*)(w + 108 * MB);

  k_prep<<<14336, 256, 0, stream>>>(Win, Wout, W1, W2, WinB, WoutB, W1B, W2B,
                                    tids, vals, dels, temb, Wv, bv, Wt, bt, hb);

  k_gemmQ<<<dim3(32, 12), 512, 0, stream>>>(hb, WinB, bin, qkv, vtb, 3072, 1024);

  k_attn<<<dim3(128, 8), 256, 0, stream>>>(qkv, vtb, attnb);

  k_gemm8<false, true><<<dim3(64, 4), 512, 0, stream>>>(
      attnb, WoutB, bout, hb, x1b, 1024, 1024);

  k_ln<<<Mm, 256, 0, stream>>>(x1b, gamma, beta, h2b);

  k_gemm8<true, false><<<dim3(64, 4), 512, 0, stream>>>(
      h2b, W1B, b1, nullptr, ff1, 1024, 1024);

  k_gemm8<false, true><<<dim3(64, 4), 512, 0, stream>>>(
      ff1, W2B, b2, h2b, x2b, 1024, 1024);

  k_ln<<<Mm, 256, 0, stream>>>(x2b, gamma, beta, h3b);

  k_pool_part<<<dim3(8, 16, 4), 256, 0, stream>>>(h3b, part);
  k_pool_fin<<<dim3(8, 4), 256, 0, stream>>>(part, out);
}

// Round 13
// 231.643 us; speedup vs baseline: 1.0422x; 1.0422x over previous
//
#include <hip/hip_runtime.h>
#include <hip/hip_bf16.h>

// EventSequenceEncoder: embed -> QKV gemm -> attention -> Wout(+res) -> LN ->
// FF1(relu) -> FF2(+res) -> LN -> mean-pool.  attn_tokens == 1/L analytically.
// R13: revert QKV to R11's 128x256 2-subphase template (best measured);
// add XCD-aware bijective block swizzle (T1) to the GEMM grids for L2
// panel locality.  Everything else identical to R11 (229.97us).

#define Dm 1024
#define Hh 16
#define Bb 8
#define Ll 1024
#define Mm 8192
#define LNEPS 1e-5f
#define QSCALE 0.18033688f   // 0.125 * log2(e)

typedef __attribute__((ext_vector_type(8))) short s16x8;
typedef __attribute__((ext_vector_type(4))) short s16x4;
typedef __attribute__((ext_vector_type(4))) float f32x4;

using bf16 = __hip_bfloat16;

__device__ __forceinline__ short f2bs(float f) {
  return __builtin_bit_cast(short, __float2bfloat16(f));
}
__device__ __forceinline__ float b2f(short s) {
  return __builtin_bit_cast(float, ((unsigned)(unsigned short)s) << 16);
}

__device__ __forceinline__ unsigned cvtpk(float lo, float hi) {
  unsigned r;
  asm("v_cvt_pk_bf16_f32 %0, %1, %2" : "=v"(r) : "v"(lo), "v"(hi));
  return r;
}

__device__ __forceinline__ void gload16(const void* g, void* l) {
  __builtin_amdgcn_global_load_lds(
      (__attribute__((address_space(1))) void*)g,
      (__attribute__((address_space(3))) void*)l, 16, 0, 0);
}

// XCD-aware bijective swizzle (grid size must be divisible by 8; ours are).
__device__ __forceinline__ int xcd_swizzle(int bid, int nwg) {
  const int cpx = nwg >> 3;                 // chunks per XCD
  return (bid & 7) * cpx + (bid >> 3);
}

// ------ prep: 4 weight f32->bf16 casts (Q-rows pre-scaled) + fused embedding -
__global__ __launch_bounds__(256) void k_prep(
    const float* __restrict__ w0, const float* __restrict__ w1,
    const float* __restrict__ w2, const float* __restrict__ w3,
    bf16* __restrict__ o0, bf16* __restrict__ o1,
    bf16* __restrict__ o2, bf16* __restrict__ o3,
    const int* __restrict__ tids, const float* __restrict__ vals,
    const float* __restrict__ dels, const float* __restrict__ temb,
    const float* __restrict__ Wv, const float* __restrict__ bv,
    const float* __restrict__ Wt, const float* __restrict__ bt,
    bf16* __restrict__ hb)
{
  const int bId = blockIdx.x;
  if (bId < 6144) {
    const float* src; bf16* dst; int rel;
    float sc = 1.f;
    if (bId < 3072)      { src = w0; dst = o0; rel = bId; if (bId < 1024) sc = QSCALE; }
    else if (bId < 4096) { src = w1; dst = o1; rel = bId - 3072; }
    else if (bId < 5120) { src = w2; dst = o2; rel = bId - 4096; }
    else                 { src = w3; dst = o3; rel = bId - 5120; }
    const size_t i = ((size_t)rel * 256 + threadIdx.x) * 4;
    const float4 v = *(const float4*)&src[i];
    s16x4 o;
    o[0] = f2bs(v.x * sc); o[1] = f2bs(v.y * sc); o[2] = f2bs(v.z * sc); o[3] = f2bs(v.w * sc);
    *(s16x4*)&dst[i] = o;
  } else {
    const int row = bId - 6144;
    const int ty = tids[row];
    const float v = vals[row], dl = dels[row];
    const int d0 = threadIdx.x * 4;
    const float4 e  = *(const float4*)&temb[(size_t)ty * Dm + d0];
    const float4 wv = *(const float4*)&Wv[d0];
    const float4 c1 = *(const float4*)&bv[d0];
    const float4 wt = *(const float4*)&Wt[d0];
    const float4 c2 = *(const float4*)&bt[d0];
    s16x4 o;
    o[0] = f2bs(e.x + v * wv.x + c1.x + dl * wt.x + c2.x);
    o[1] = f2bs(e.y + v * wv.y + c1.y + dl * wt.y + c2.y);
    o[2] = f2bs(e.z + v * wv.z + c1.z + dl * wt.z + c2.z);
    o[3] = f2bs(e.w + v * wv.w + c1.w + dl * wt.w + c2.w);
    *(s16x4*)((short*)hb + (size_t)row * Dm + d0) = o;
  }
}

// ---------------- 2-subphase GEMM: out = A @ Bt^T + bias (+bf16 res) --------
// BM=128, BN=256, BK=64, 8 waves (2M x 4N), per-wave 64x64 out.
// QS: scale bias for cols<1024 (Q part of QKV, matches pre-scaled Win rows).
// VT: redirect cols>=2048 (V part of QKV) into vt[b,h][dh][l] layout.
// Grid is 1-D with XCD-aware swizzle: bm = swz / nbn, bn = swz % nbn.
template<bool RELU, bool RES, bool QS, bool VT>
__global__ __launch_bounds__(512) void k_gemm8(
    const bf16* __restrict__ A, const bf16* __restrict__ Bt,
    const float* __restrict__ bias, const bf16* __restrict__ res,
    bf16* __restrict__ outB, bf16* __restrict__ vt, const int N, const int K)
{
  __shared__ __attribute__((aligned(16))) short lds[49152];  // 2 x (8192 A + 16384 B)
  const int tid = threadIdx.x, lane = tid & 63, wave = tid >> 6;
  const int wr = wave >> 2, wc = wave & 3;
  const int l15 = lane & 15, lg = (lane >> 4) & 3;
  const int nbn = N >> 8;
  const int swzb = xcd_swizzle(blockIdx.x, gridDim.x);
  const int bm = swzb / nbn, bn = swzb % nbn;
  const int NT = K >> 6;

  const int rl = tid >> 3;
  const int swz = ((tid & 7) ^ (rl & 7)) * 8;
  const bf16* aSrc = A  + (size_t)(bm * 128 + rl) * K + swz;
  const bf16* bSrc = Bt + (size_t)(bn * 256 + rl) * K + swz;

  f32x4 acc[4][4] = {};

  auto stageA = [&](int t, int h) {
    gload16(aSrc + (size_t)h * 64 * K + t * 64,
            &lds[(t & 1) * 24576 + h * 4096 + tid * 8]);
  };
  auto stageB = [&](int t, int h) {
    gload16(bSrc + (size_t)h * 128 * K + t * 64,
            &lds[(t & 1) * 24576 + 8192 + h * 8192 + tid * 8]);
    gload16(bSrc + (size_t)(h * 128 + 64) * K + t * 64,
            &lds[(t & 1) * 24576 + 8192 + h * 8192 + 4096 + tid * 8]);
  };

  stageA(0, 0); stageA(0, 1); stageB(0, 0); stageB(0, 1);
  if (NT > 1) { stageA(1, 0); stageA(1, 1); }
  asm volatile("s_waitcnt vmcnt(2)" ::: "memory");
  __builtin_amdgcn_sched_barrier(0);
  __builtin_amdgcn_s_barrier();

  for (int t = 0; t < NT; ++t) {
    const int cb = (t & 1) * 24576;
    s16x8 fa[4][2], fb[2][2];

    // ---- SP0: read all fa + fb(n=0,1); stage B(t+1) both halves
#pragma unroll
    for (int m = 0; m < 4; ++m)
#pragma unroll
      for (int ks = 0; ks < 2; ++ks) {
        const int row = wr * 64 + m * 16 + l15;
        fa[m][ks] = *(const s16x8*)&lds[cb + row * 64 + (((ks * 4 + lg) ^ (row & 7)) << 3)];
      }
#pragma unroll
    for (int n = 0; n < 2; ++n)
#pragma unroll
      for (int ks = 0; ks < 2; ++ks) {
        const int row = wc * 64 + n * 16 + l15;
        fb[n][ks] = *(const s16x8*)&lds[cb + 8192 + row * 64 + (((ks * 4 + lg) ^ (row & 7)) << 3)];
      }
    if (t + 1 < NT) { stageB(t + 1, 0); stageB(t + 1, 1); }
    __builtin_amdgcn_s_barrier();
    asm volatile("s_waitcnt lgkmcnt(0)" ::: "memory");
    __builtin_amdgcn_sched_barrier(0);
    __builtin_amdgcn_s_setprio(1);
#pragma unroll
    for (int m = 0; m < 4; ++m)
#pragma unroll
      for (int n = 0; n < 2; ++n)
#pragma unroll
        for (int ks = 0; ks < 2; ++ks)
          acc[m][n] = __builtin_amdgcn_mfma_f32_16x16x32_bf16(fa[m][ks], fb[n][ks], acc[m][n], 0, 0, 0);
    __builtin_amdgcn_s_setprio(0);
    __builtin_amdgcn_s_barrier();

    // ---- SP1: read fb(n=2,3); stage A(t+2) into current buf (A region dead)
#pragma unroll
    for (int n = 0; n < 2; ++n)
#pragma unroll
      for (int ks = 0; ks < 2; ++ks) {
        const int row = wc * 64 + (2 + n) * 16 + l15;
        fb[n][ks] = *(const s16x8*)&lds[cb + 8192 + row * 64 + (((ks * 4 + lg) ^ (row & 7)) << 3)];
      }
    if (t + 2 < NT) { stageA(t + 2, 0); stageA(t + 2, 1); }
    __builtin_amdgcn_s_barrier();
    asm volatile("s_waitcnt lgkmcnt(0)" ::: "memory");
    __builtin_amdgcn_sched_barrier(0);
    __builtin_amdgcn_s_setprio(1);
#pragma unroll
    for (int m = 0; m < 4; ++m)
#pragma unroll
      for (int n = 0; n < 2; ++n)
#pragma unroll
        for (int ks = 0; ks < 2; ++ks)
          acc[m][2 + n] = __builtin_amdgcn_mfma_f32_16x16x32_bf16(fa[m][ks], fb[n][ks], acc[m][2 + n], 0, 0, 0);
    __builtin_amdgcn_s_setprio(0);

    if (t + 1 < NT) {
      if (t + 2 < NT) asm volatile("s_waitcnt vmcnt(2)" ::: "memory");
      else            asm volatile("s_waitcnt vmcnt(0)" ::: "memory");
      __builtin_amdgcn_sched_barrier(0);
      __builtin_amdgcn_s_barrier();
    }
  }

  // epilogue
#pragma unroll
  for (int n = 0; n < 4; ++n) {
    const int col = bn * 256 + wc * 64 + n * 16 + l15;
    float bc = bias[col];
    if constexpr (QS) { if (col < 1024) bc *= QSCALE; }
    if constexpr (VT) {
      if (col >= 2048) {
        const int hh = (col - 2048) >> 6, dh = (col - 2048) & 63;
#pragma unroll
        for (int m = 0; m < 4; ++m) {
          const size_t row0 = (size_t)bm * 128 + wr * 64 + m * 16 + lg * 4;
          const int bb = (int)(row0 >> 10), l0 = (int)(row0 & 1023);
          s16x4 pk;
#pragma unroll
          for (int i = 0; i < 4; ++i) pk[i] = f2bs(acc[m][n][i] + bc);
          *(s16x4*)((short*)vt + ((size_t)((bb * 16 + hh) * 64 + dh)) * Ll + l0) = pk;
        }
        continue;
      }
    }
#pragma unroll
    for (int m = 0; m < 4; ++m) {
#pragma unroll
      for (int i = 0; i < 4; ++i) {
        const size_t row = (size_t)bm * 128 + wr * 64 + m * 16 + lg * 4 + i;
        float v = acc[m][n][i] + bc;
        if constexpr (RES)  v += b2f(((const short*)res)[row * N + col]);
        if constexpr (RELU) v = fmaxf(v, 0.f);
        outB[row * N + col] = __float2bfloat16(v);
      }
    }
  }
}

// ---------------- attention (R5): swapped QK^T, wave-private P, QBLK=128 -----
__global__ __launch_bounds__(256) void k_attn(
    const bf16* __restrict__ qkv, const bf16* __restrict__ vt, bf16* __restrict__ attnb)
{
  const int bh = blockIdx.x;
  const int qb = blockIdx.y;
  const int b = bh >> 4, h = bh & 15;
  __shared__ __attribute__((aligned(16))) short lK[8192];   // 2 x [64][64] swz
  __shared__ __attribute__((aligned(16))) short lV[8192];   // 2 x [64][64] swz
  __shared__ __attribute__((aligned(16))) short lP[8192];   // [128][64] swz, wave-private rows
  const int tid = threadIdx.x, lane = tid & 63, wave = tid >> 6;
  const int l15 = lane & 15, lg = lane >> 4;
  const int qrow = wave * 32;
  const int l7 = l15 & 7;

  s16x8 qf[2][2];
#pragma unroll
  for (int mq = 0; mq < 2; ++mq)
#pragma unroll
    for (int ks = 0; ks < 2; ++ks)
      qf[mq][ks] = *(const s16x8*)((const short*)qkv +
          ((size_t)(b * Ll + qb * 128 + qrow + mq * 16 + l15)) * 3072 + h * 64 + ks * 32 + lg * 8);

  f32x4 o[2][4] = {};
  float rs[2] = {0.f, 0.f};

  const int sr = tid >> 3;
  const int swz = (tid & 7) ^ (sr & 7);

  auto stage = [&](int mc) {
    const int bo = (mc & 1) * 4096;
    const bf16* gk = qkv + ((size_t)(b * Ll + mc * 64 + sr)) * 3072 + 1024 + h * 64 + swz * 8;
    gload16(gk,                     &lK[bo + tid * 8]);
    gload16(gk + (size_t)32 * 3072, &lK[bo + 2048 + tid * 8]);
    const bf16* gv = vt + ((size_t)(bh * 64 + sr)) * Ll + mc * 64 + swz * 8;
    gload16(gv,                   &lV[bo + tid * 8]);
    gload16(gv + (size_t)32 * Ll, &lV[bo + 2048 + tid * 8]);
  };

  stage(0);

  for (int mc = 0; mc < 16; ++mc) {
    asm volatile("s_waitcnt vmcnt(0)" ::: "memory");
    __builtin_amdgcn_s_barrier();
    __builtin_amdgcn_sched_barrier(0);
    if (mc + 1 < 16) stage(mc + 1);
    const int bo = (mc & 1) * 4096;

    f32x4 st[2][4] = {};
    __builtin_amdgcn_s_setprio(1);
#pragma unroll
    for (int ks = 0; ks < 2; ++ks) {
#pragma unroll
      for (int n = 0; n < 4; ++n) {
        const int kr = n * 16 + l15;
        const s16x8 kf = *(const s16x8*)&lK[bo + kr * 64 + (((ks * 4 + lg) ^ l7) << 3)];
        st[0][n] = __builtin_amdgcn_mfma_f32_16x16x32_bf16(kf, qf[0][ks], st[0][n], 0, 0, 0);
        st[1][n] = __builtin_amdgcn_mfma_f32_16x16x32_bf16(kf, qf[1][ks], st[1][n], 0, 0, 0);
      }
    }
    __builtin_amdgcn_s_setprio(0);

#pragma unroll
    for (int mq = 0; mq < 2; ++mq) {
      const int qr = qrow + mq * 16 + l15;
      short* prow = &lP[qr * 64];
      float loc = 0.f;
#pragma unroll
      for (int n = 0; n < 4; ++n) {
        const float e0 = __builtin_amdgcn_exp2f(st[mq][n][0]);
        const float e1 = __builtin_amdgcn_exp2f(st[mq][n][1]);
        const float e2 = __builtin_amdgcn_exp2f(st[mq][n][2]);
        const float e3 = __builtin_amdgcn_exp2f(st[mq][n][3]);
        loc += (e0 + e1) + (e2 + e3);
        const unsigned c0 = cvtpk(e0, e1);
        const unsigned c1 = cvtpk(e2, e3);
        const int col0 = n * 16 + lg * 4;
        const int scol = ((((col0 >> 3) ^ (qr & 7)) << 3) | (col0 & 7));
        *(unsigned*)&prow[scol]     = c0;
        *(unsigned*)&prow[scol + 2] = c1;
      }
      rs[mq] += loc;
    }

    __builtin_amdgcn_s_setprio(1);
#pragma unroll
    for (int ks = 0; ks < 2; ++ks) {
      s16x8 pa[2];
#pragma unroll
      for (int mq = 0; mq < 2; ++mq) {
        const int qr = qrow + mq * 16 + l15;
        pa[mq] = *(const s16x8*)&lP[qr * 64 + (((ks * 4 + lg) ^ (qr & 7)) << 3)];
      }
#pragma unroll
      for (int dn = 0; dn < 4; ++dn) {
        const int vr = dn * 16 + l15;
        const s16x8 vf = *(const s16x8*)&lV[bo + vr * 64 + (((ks * 4 + lg) ^ l7) << 3)];
        o[0][dn] = __builtin_amdgcn_mfma_f32_16x16x32_bf16(pa[0], vf, o[0][dn], 0, 0, 0);
        o[1][dn] = __builtin_amdgcn_mfma_f32_16x16x32_bf16(pa[1], vf, o[1][dn], 0, 0, 0);
      }
    }
    __builtin_amdgcn_s_setprio(0);
    asm volatile("s_waitcnt lgkmcnt(0)" ::: "memory");
  }

#pragma unroll
  for (int mq = 0; mq < 2; ++mq) {
    rs[mq] += __shfl_xor(rs[mq], 16);
    rs[mq] += __shfl_xor(rs[mq], 32);
  }
#pragma unroll
  for (int mq = 0; mq < 2; ++mq) {
    float inv[4];
#pragma unroll
    for (int i = 0; i < 4; ++i)
      inv[i] = 1.f / __shfl(rs[mq], lg * 4 + i);
#pragma unroll
    for (int dn = 0; dn < 4; ++dn) {
#pragma unroll
      for (int i = 0; i < 4; ++i) {
        const int q = qb * 128 + qrow + mq * 16 + lg * 4 + i;
        attnb[((size_t)(b * Ll + q)) * Dm + h * 64 + dn * 16 + l15] =
            __float2bfloat16(o[mq][dn][i] * inv[i]);
      }
    }
  }
}

// ---------------- LayerNorm: bf16 in, bf16 out (one row per block) ----------
__global__ __launch_bounds__(256) void k_ln(const bf16* __restrict__ x,
    const float* __restrict__ gamma, const float* __restrict__ beta,
    bf16* __restrict__ y)
{
  const size_t row = blockIdx.x;
  const int d0 = threadIdx.x * 4;
  const s16x4 xv = *(const s16x4*)((const short*)x + row * Dm + d0);
  float f0 = b2f(xv[0]), f1 = b2f(xv[1]), f2 = b2f(xv[2]), f3 = b2f(xv[3]);
  float s  = (f0 + f1) + (f2 + f3);
  float ss = (f0 * f0 + f1 * f1) + (f2 * f2 + f3 * f3);
#pragma unroll
  for (int m = 1; m < 64; m <<= 1) { s += __shfl_xor(s, m); ss += __shfl_xor(ss, m); }
  __shared__ float red[8];
  const int wv = threadIdx.x >> 6;
  if ((threadIdx.x & 63) == 0) { red[wv] = s; red[4 + wv] = ss; }
  __syncthreads();
  s  = red[0] + red[1] + red[2] + red[3];
  ss = red[4] + red[5] + red[6] + red[7];
  const float mu = s * (1.f / Dm);
  const float rstd = rsqrtf(ss * (1.f / Dm) - mu * mu + LNEPS);
  const float4 g  = *(const float4*)&gamma[d0];
  const float4 be = *(const float4*)&beta[d0];
  s16x4 o;
  o[0] = f2bs((f0 - mu) * rstd * g.x + be.x);
  o[1] = f2bs((f1 - mu) * rstd * g.y + be.y);
  o[2] = f2bs((f2 - mu) * rstd * g.z + be.z);
  o[3] = f2bs((f3 - mu) * rstd * g.w + be.w);
  *(s16x4*)((short*)y + row * Dm + d0) = o;
}

// ---------------- mean pool (bf16 in) ----------------
__global__ __launch_bounds__(256) void k_pool_part(const bf16* __restrict__ h3, float* __restrict__ part)
{
  const int b = blockIdx.x, lcn = blockIdx.y, dz = blockIdx.z;
  const int d = dz * 256 + threadIdx.x;
  float s = 0.f;
#pragma unroll 4
  for (int l = 0; l < 64; ++l)
    s += b2f(((const short*)h3)[((size_t)(b * Ll + lcn * 64 + l)) * Dm + d]);
  part[((size_t)(b * 16 + lcn)) * Dm + d] = s;
}

__global__ __launch_bounds__(256) void k_pool_fin(const float* __restrict__ part, float* __restrict__ out)
{
  const int b = blockIdx.x;
  const int d = blockIdx.y * 256 + threadIdx.x;
  float s = 0.f;
#pragma unroll
  for (int c = 0; c < 16; ++c) s += part[((size_t)(b * 16 + c)) * Dm + d];
  out[b * Dm + d] = s * (1.f / Ll);
  out[(size_t)Mm + b * Dm + d] = 1.f / Ll;  // attn_tokens == 1/L analytically
}

extern "C" void kernel_launch(void* const* d_in, const int* in_sizes, int n_in,
                              void* d_out, int out_size, void* d_ws, size_t ws_size,
                              hipStream_t stream) {
  const int*   tids  = (const int*)  d_in[0];
  const float* vals  = (const float*)d_in[1];
  const float* dels  = (const float*)d_in[2];
  const float* temb  = (const float*)d_in[3];
  const float* Wv    = (const float*)d_in[4];
  const float* bv    = (const float*)d_in[5];
  const float* Wt    = (const float*)d_in[6];
  const float* bt    = (const float*)d_in[7];
  const float* Win   = (const float*)d_in[8];
  const float* bin   = (const float*)d_in[9];
  const float* Wout  = (const float*)d_in[10];
  const float* bout  = (const float*)d_in[11];
  const float* W1    = (const float*)d_in[12];
  const float* b1    = (const float*)d_in[13];
  const float* W2    = (const float*)d_in[14];
  const float* b2    = (const float*)d_in[15];
  const float* gamma = (const float*)d_in[16];
  const float* beta  = (const float*)d_in[17];
  float* out = (float*)d_out;

  char* w = (char*)d_ws;
  const size_t MB = 1ull << 20;
  bf16*  hb    = (bf16*) (w + 0);         // [0,16)    h bf16 (QKV-A, Wout-res)
  bf16*  qkv   = (bf16*) (w + 16 * MB);   // [16,64)   q,k bf16 (V redirected)
  bf16*  vtb   = (bf16*) (w + 64 * MB);   // [64,80)   v^T (written by QKV gemm)
  bf16*  attnb = (bf16*) (w + 80 * MB);   // [80,96)   attn out (dead after Wout)
  bf16*  x1b   = (bf16*) (w + 16 * MB);   // [16,32)   h+attnout (qkv dead)
  bf16*  h2b   = (bf16*) (w + 32 * MB);   // [32,48)   LN1 out (FF1-A, FF2-res)
  bf16*  ff1   = (bf16*) (w + 48 * MB);   // [48,64)   relu(ff1)
  bf16*  x2b   = (bf16*) (w + 64 * MB);   // [64,80)   h2+ff2 (vtb dead)
  bf16*  h3b   = (bf16*) (w + 80 * MB);   // [80,96)   LN2 out (attnb dead)
  bf16*  WinB  = (bf16*) (w + 96 * MB);
  bf16*  WoutB = (bf16*) (w + 102 * MB);
  bf16*  W1B   = (bf16*) (w + 104 * MB);
  bf16*  W2B   = (bf16*) (w + 106 * MB);
  float* part  = (float*)(w + 108 * MB);

  k_prep<<<14336, 256, 0, stream>>>(Win, Wout, W1, W2, WinB, WoutB, W1B, W2B,
                                    tids, vals, dels, temb, Wv, bv, Wt, bt, hb);

  k_gemm8<false, false, true, true><<<768, 512, 0, stream>>>(
      hb, WinB, bin, nullptr, qkv, vtb, 3072, 1024);

  k_attn<<<dim3(128, 8), 256, 0, stream>>>(qkv, vtb, attnb);

  k_gemm8<false, true, false, false><<<256, 512, 0, stream>>>(
      attnb, WoutB, bout, hb, x1b, nullptr, 1024, 1024);

  k_ln<<<Mm, 256, 0, stream>>>(x1b, gamma, beta, h2b);

  k_gemm8<true, false, false, false><<<256, 512, 0, stream>>>(
      h2b, W1B, b1, nullptr, ff1, nullptr, 1024, 1024);

  k_gemm8<false, true, false, false><<<256, 512, 0, stream>>>(
      ff1, W2B, b2, h2b, x2b, nullptr, 1024, 1024);

  k_ln<<<Mm, 256, 0, stream>>>(x2b, gamma, beta, h3b);

  k_pool_part<<<dim3(8, 16, 4), 256, 0, stream>>>(h3b, part);
  k_pool_fin<<<dim3(8, 4), 256, 0, stream>>>(part, out);
}

// Round 15
// 229.627 us; speedup vs baseline: 1.0513x; 1.0088x over previous
//
#include <hip/hip_runtime.h>
#include <hip/hip_bf16.h>

// EventSequenceEncoder: embed -> QKV gemm -> attention -> Wout(+res) -> LN ->
// FF1(relu) -> FF2(+res) -> LN -> mean-pool.  attn_tokens == 1/L analytically.
// R15: R11 + RACE FIX: __builtin_amdgcn_s_barrier() is NOT a compiler memory
// fence -- LLVM could hoist global_load_lds (stage) above a barrier, letting
// one wave's DMA overwrite an LDS region other waves are still ds_reading
// (manifested as rare post-timing divergence in R14). Every barrier in the
// GEMM/attn is now barrier_fenced(): s_barrier + zero-cost asm memory fence.

#define Dm 1024
#define Hh 16
#define Bb 8
#define Ll 1024
#define Mm 8192
#define LNEPS 1e-5f
#define QSCALE 0.18033688f   // 0.125 * log2(e)

typedef __attribute__((ext_vector_type(8))) short s16x8;
typedef __attribute__((ext_vector_type(4))) short s16x4;
typedef __attribute__((ext_vector_type(4))) float f32x4;

using bf16 = __hip_bfloat16;

__device__ __forceinline__ short f2bs(float f) {
  return __builtin_bit_cast(short, __float2bfloat16(f));
}
__device__ __forceinline__ float b2f(short s) {
  return __builtin_bit_cast(float, ((unsigned)(unsigned short)s) << 16);
}

__device__ __forceinline__ unsigned cvtpk(float lo, float hi) {
  unsigned r;
  asm("v_cvt_pk_bf16_f32 %0, %1, %2" : "=v"(r) : "v"(lo), "v"(hi));
  return r;
}

__device__ __forceinline__ void gload16(const void* g, void* l) {
  __builtin_amdgcn_global_load_lds(
      (__attribute__((address_space(1))) void*)g,
      (__attribute__((address_space(3))) void*)l, 16, 0, 0);
}

// s_barrier + compiler memory fence: raw s_barrier is convergent but NOT a
// memory fence for the optimizer -- memory ops (incl. global_load_lds) could
// be hoisted/sunk across it.  The empty asm pins them at zero runtime cost.
__device__ __forceinline__ void barrier_fenced() {
  __builtin_amdgcn_s_barrier();
  asm volatile("" ::: "memory");
}

// ------ prep: 4 weight f32->bf16 casts (Q-rows pre-scaled) + fused embedding -
__global__ __launch_bounds__(256) void k_prep(
    const float* __restrict__ w0, const float* __restrict__ w1,
    const float* __restrict__ w2, const float* __restrict__ w3,
    bf16* __restrict__ o0, bf16* __restrict__ o1,
    bf16* __restrict__ o2, bf16* __restrict__ o3,
    const int* __restrict__ tids, const float* __restrict__ vals,
    const float* __restrict__ dels, const float* __restrict__ temb,
    const float* __restrict__ Wv, const float* __restrict__ bv,
    const float* __restrict__ Wt, const float* __restrict__ bt,
    bf16* __restrict__ hb)
{
  const int bId = blockIdx.x;
  if (bId < 6144) {
    const float* src; bf16* dst; int rel;
    float sc = 1.f;
    if (bId < 3072)      { src = w0; dst = o0; rel = bId; if (bId < 1024) sc = QSCALE; }
    else if (bId < 4096) { src = w1; dst = o1; rel = bId - 3072; }
    else if (bId < 5120) { src = w2; dst = o2; rel = bId - 4096; }
    else                 { src = w3; dst = o3; rel = bId - 5120; }
    const size_t i = ((size_t)rel * 256 + threadIdx.x) * 4;
    const float4 v = *(const float4*)&src[i];
    s16x4 o;
    o[0] = f2bs(v.x * sc); o[1] = f2bs(v.y * sc); o[2] = f2bs(v.z * sc); o[3] = f2bs(v.w * sc);
    *(s16x4*)&dst[i] = o;
  } else {
    const int row = bId - 6144;
    const int ty = tids[row];
    const float v = vals[row], dl = dels[row];
    const int d0 = threadIdx.x * 4;
    const float4 e  = *(const float4*)&temb[(size_t)ty * Dm + d0];
    const float4 wv = *(const float4*)&Wv[d0];
    const float4 c1 = *(const float4*)&bv[d0];
    const float4 wt = *(const float4*)&Wt[d0];
    const float4 c2 = *(const float4*)&bt[d0];
    s16x4 o;
    o[0] = f2bs(e.x + v * wv.x + c1.x + dl * wt.x + c2.x);
    o[1] = f2bs(e.y + v * wv.y + c1.y + dl * wt.y + c2.y);
    o[2] = f2bs(e.z + v * wv.z + c1.z + dl * wt.z + c2.z);
    o[3] = f2bs(e.w + v * wv.w + c1.w + dl * wt.w + c2.w);
    *(s16x4*)((short*)hb + (size_t)row * Dm + d0) = o;
  }
}

// ---------------- 2-subphase GEMM: out = A @ Bt^T + bias (+bf16 res) --------
// BM=128, BN=256, BK=64, 8 waves (2M x 4N), per-wave 64x64 out.
// QS: scale bias for cols<1024 (Q part of QKV, matches pre-scaled Win rows).
// VT: redirect cols>=2048 (V part of QKV) into vt[b,h][dh][l] layout.
template<bool RELU, bool RES, bool QS, bool VT>
__global__ __launch_bounds__(512) void k_gemm8(
    const bf16* __restrict__ A, const bf16* __restrict__ Bt,
    const float* __restrict__ bias, const bf16* __restrict__ res,
    bf16* __restrict__ outB, bf16* __restrict__ vt, const int N, const int K)
{
  __shared__ __attribute__((aligned(16))) short lds[49152];  // 2 x (8192 A + 16384 B)
  const int tid = threadIdx.x, lane = tid & 63, wave = tid >> 6;
  const int wr = wave >> 2, wc = wave & 3;
  const int l15 = lane & 15, lg = (lane >> 4) & 3;
  const int bm = blockIdx.x, bn = blockIdx.y;
  const int NT = K >> 6;

  const int rl = tid >> 3;
  const int swz = ((tid & 7) ^ (rl & 7)) * 8;
  const bf16* aSrc = A  + (size_t)(bm * 128 + rl) * K + swz;
  const bf16* bSrc = Bt + (size_t)(bn * 256 + rl) * K + swz;

  f32x4 acc[4][4] = {};

  auto stageA = [&](int t, int h) {
    gload16(aSrc + (size_t)h * 64 * K + t * 64,
            &lds[(t & 1) * 24576 + h * 4096 + tid * 8]);
  };
  auto stageB = [&](int t, int h) {
    gload16(bSrc + (size_t)h * 128 * K + t * 64,
            &lds[(t & 1) * 24576 + 8192 + h * 8192 + tid * 8]);
    gload16(bSrc + (size_t)(h * 128 + 64) * K + t * 64,
            &lds[(t & 1) * 24576 + 8192 + h * 8192 + 4096 + tid * 8]);
  };

  stageA(0, 0); stageA(0, 1); stageB(0, 0); stageB(0, 1);
  if (NT > 1) { stageA(1, 0); stageA(1, 1); }
  asm volatile("s_waitcnt vmcnt(2)" ::: "memory");
  __builtin_amdgcn_sched_barrier(0);
  barrier_fenced();

  for (int t = 0; t < NT; ++t) {
    const int cb = (t & 1) * 24576;
    s16x8 fa[4][2], fb[2][2];

    // ---- SP0: read all fa + fb(n=0,1); stage B(t+1) both halves
#pragma unroll
    for (int m = 0; m < 4; ++m)
#pragma unroll
      for (int ks = 0; ks < 2; ++ks) {
        const int row = wr * 64 + m * 16 + l15;
        fa[m][ks] = *(const s16x8*)&lds[cb + row * 64 + (((ks * 4 + lg) ^ (row & 7)) << 3)];
      }
#pragma unroll
    for (int n = 0; n < 2; ++n)
#pragma unroll
      for (int ks = 0; ks < 2; ++ks) {
        const int row = wc * 64 + n * 16 + l15;
        fb[n][ks] = *(const s16x8*)&lds[cb + 8192 + row * 64 + (((ks * 4 + lg) ^ (row & 7)) << 3)];
      }
    if (t + 1 < NT) { stageB(t + 1, 0); stageB(t + 1, 1); }
    barrier_fenced();
    asm volatile("s_waitcnt lgkmcnt(0)" ::: "memory");
    __builtin_amdgcn_sched_barrier(0);
    __builtin_amdgcn_s_setprio(1);
#pragma unroll
    for (int m = 0; m < 4; ++m)
#pragma unroll
      for (int n = 0; n < 2; ++n)
#pragma unroll
        for (int ks = 0; ks < 2; ++ks)
          acc[m][n] = __builtin_amdgcn_mfma_f32_16x16x32_bf16(fa[m][ks], fb[n][ks], acc[m][n], 0, 0, 0);
    __builtin_amdgcn_s_setprio(0);
    barrier_fenced();

    // ---- SP1: read fb(n=2,3); stage A(t+2) into current buf (A region dead)
#pragma unroll
    for (int n = 0; n < 2; ++n)
#pragma unroll
      for (int ks = 0; ks < 2; ++ks) {
        const int row = wc * 64 + (2 + n) * 16 + l15;
        fb[n][ks] = *(const s16x8*)&lds[cb + 8192 + row * 64 + (((ks * 4 + lg) ^ (row & 7)) << 3)];
      }
    if (t + 2 < NT) { stageA(t + 2, 0); stageA(t + 2, 1); }
    barrier_fenced();
    asm volatile("s_waitcnt lgkmcnt(0)" ::: "memory");
    __builtin_amdgcn_sched_barrier(0);
    __builtin_amdgcn_s_setprio(1);
#pragma unroll
    for (int m = 0; m < 4; ++m)
#pragma unroll
      for (int n = 0; n < 2; ++n)
#pragma unroll
        for (int ks = 0; ks < 2; ++ks)
          acc[m][2 + n] = __builtin_amdgcn_mfma_f32_16x16x32_bf16(fa[m][ks], fb[n][ks], acc[m][2 + n], 0, 0, 0);
    __builtin_amdgcn_s_setprio(0);

    if (t + 1 < NT) {
      if (t + 2 < NT) asm volatile("s_waitcnt vmcnt(2)" ::: "memory");
      else            asm volatile("s_waitcnt vmcnt(0)" ::: "memory");
      __builtin_amdgcn_sched_barrier(0);
      barrier_fenced();
    }
  }

  // epilogue
#pragma unroll
  for (int n = 0; n < 4; ++n) {
    const int col = bn * 256 + wc * 64 + n * 16 + l15;
    float bc = bias[col];
    if constexpr (QS) { if (col < 1024) bc *= QSCALE; }
    if constexpr (VT) {
      if (col >= 2048) {
        const int hh = (col - 2048) >> 6, dh = (col - 2048) & 63;
#pragma unroll
        for (int m = 0; m < 4; ++m) {
          const size_t row0 = (size_t)bm * 128 + wr * 64 + m * 16 + lg * 4;
          const int bb = (int)(row0 >> 10), l0 = (int)(row0 & 1023);
          s16x4 pk;
#pragma unroll
          for (int i = 0; i < 4; ++i) pk[i] = f2bs(acc[m][n][i] + bc);
          *(s16x4*)((short*)vt + ((size_t)((bb * 16 + hh) * 64 + dh)) * Ll + l0) = pk;
        }
        continue;
      }
    }
#pragma unroll
    for (int m = 0; m < 4; ++m) {
#pragma unroll
      for (int i = 0; i < 4; ++i) {
        const size_t row = (size_t)bm * 128 + wr * 64 + m * 16 + lg * 4 + i;
        float v = acc[m][n][i] + bc;
        if constexpr (RES)  v += b2f(((const short*)res)[row * N + col]);
        if constexpr (RELU) v = fmaxf(v, 0.f);
        outB[row * N + col] = __float2bfloat16(v);
      }
    }
  }
}

// ---------------- attention (R5): swapped QK^T, wave-private P, QBLK=128 -----
__global__ __launch_bounds__(256) void k_attn(
    const bf16* __restrict__ qkv, const bf16* __restrict__ vt, bf16* __restrict__ attnb)
{
  const int bh = blockIdx.x;
  const int qb = blockIdx.y;
  const int b = bh >> 4, h = bh & 15;
  __shared__ __attribute__((aligned(16))) short lK[8192];   // 2 x [64][64] swz
  __shared__ __attribute__((aligned(16))) short lV[8192];   // 2 x [64][64] swz
  __shared__ __attribute__((aligned(16))) short lP[8192];   // [128][64] swz, wave-private rows
  const int tid = threadIdx.x, lane = tid & 63, wave = tid >> 6;
  const int l15 = lane & 15, lg = lane >> 4;
  const int qrow = wave * 32;
  const int l7 = l15 & 7;

  s16x8 qf[2][2];
#pragma unroll
  for (int mq = 0; mq < 2; ++mq)
#pragma unroll
    for (int ks = 0; ks < 2; ++ks)
      qf[mq][ks] = *(const s16x8*)((const short*)qkv +
          ((size_t)(b * Ll + qb * 128 + qrow + mq * 16 + l15)) * 3072 + h * 64 + ks * 32 + lg * 8);

  f32x4 o[2][4] = {};
  float rs[2] = {0.f, 0.f};

  const int sr = tid >> 3;
  const int swz = (tid & 7) ^ (sr & 7);

  auto stage = [&](int mc) {
    const int bo = (mc & 1) * 4096;
    const bf16* gk = qkv + ((size_t)(b * Ll + mc * 64 + sr)) * 3072 + 1024 + h * 64 + swz * 8;
    gload16(gk,                     &lK[bo + tid * 8]);
    gload16(gk + (size_t)32 * 3072, &lK[bo + 2048 + tid * 8]);
    const bf16* gv = vt + ((size_t)(bh * 64 + sr)) * Ll + mc * 64 + swz * 8;
    gload16(gv,                   &lV[bo + tid * 8]);
    gload16(gv + (size_t)32 * Ll, &lV[bo + 2048 + tid * 8]);
  };

  stage(0);

  for (int mc = 0; mc < 16; ++mc) {
    // drain own stage loads + LDS reads of prev iter, then sync; the fence in
    // barrier_fenced() keeps stage(mc+1) (and compute reads) BELOW the barrier.
    asm volatile("s_waitcnt vmcnt(0)" ::: "memory");
    barrier_fenced();
    __builtin_amdgcn_sched_barrier(0);
    if (mc + 1 < 16) stage(mc + 1);
    const int bo = (mc & 1) * 4096;

    f32x4 st[2][4] = {};
    __builtin_amdgcn_s_setprio(1);
#pragma unroll
    for (int ks = 0; ks < 2; ++ks) {
#pragma unroll
      for (int n = 0; n < 4; ++n) {
        const int kr = n * 16 + l15;
        const s16x8 kf = *(const s16x8*)&lK[bo + kr * 64 + (((ks * 4 + lg) ^ l7) << 3)];
        st[0][n] = __builtin_amdgcn_mfma_f32_16x16x32_bf16(kf, qf[0][ks], st[0][n], 0, 0, 0);
        st[1][n] = __builtin_amdgcn_mfma_f32_16x16x32_bf16(kf, qf[1][ks], st[1][n], 0, 0, 0);
      }
    }
    __builtin_amdgcn_s_setprio(0);

#pragma unroll
    for (int mq = 0; mq < 2; ++mq) {
      const int qr = qrow + mq * 16 + l15;
      short* prow = &lP[qr * 64];
      float loc = 0.f;
#pragma unroll
      for (int n = 0; n < 4; ++n) {
        const float e0 = __builtin_amdgcn_exp2f(st[mq][n][0]);
        const float e1 = __builtin_amdgcn_exp2f(st[mq][n][1]);
        const float e2 = __builtin_amdgcn_exp2f(st[mq][n][2]);
        const float e3 = __builtin_amdgcn_exp2f(st[mq][n][3]);
        loc += (e0 + e1) + (e2 + e3);
        const unsigned c0 = cvtpk(e0, e1);
        const unsigned c1 = cvtpk(e2, e3);
        const int col0 = n * 16 + lg * 4;
        const int scol = ((((col0 >> 3) ^ (qr & 7)) << 3) | (col0 & 7));
        *(unsigned*)&prow[scol]     = c0;
        *(unsigned*)&prow[scol + 2] = c1;
      }
      rs[mq] += loc;
    }

    __builtin_amdgcn_s_setprio(1);
#pragma unroll
    for (int ks = 0; ks < 2; ++ks) {
      s16x8 pa[2];
#pragma unroll
      for (int mq = 0; mq < 2; ++mq) {
        const int qr = qrow + mq * 16 + l15;
        pa[mq] = *(const s16x8*)&lP[qr * 64 + (((ks * 4 + lg) ^ (qr & 7)) << 3)];
      }
#pragma unroll
      for (int dn = 0; dn < 4; ++dn) {
        const int vr = dn * 16 + l15;
        const s16x8 vf = *(const s16x8*)&lV[bo + vr * 64 + (((ks * 4 + lg) ^ l7) << 3)];
        o[0][dn] = __builtin_amdgcn_mfma_f32_16x16x32_bf16(pa[0], vf, o[0][dn], 0, 0, 0);
        o[1][dn] = __builtin_amdgcn_mfma_f32_16x16x32_bf16(pa[1], vf, o[1][dn], 0, 0, 0);
      }
    }
    __builtin_amdgcn_s_setprio(0);
    asm volatile("s_waitcnt lgkmcnt(0)" ::: "memory");
    __builtin_amdgcn_sched_barrier(0);
  }

#pragma unroll
  for (int mq = 0; mq < 2; ++mq) {
    rs[mq] += __shfl_xor(rs[mq], 16);
    rs[mq] += __shfl_xor(rs[mq], 32);
  }
#pragma unroll
  for (int mq = 0; mq < 2; ++mq) {
    float inv[4];
#pragma unroll
    for (int i = 0; i < 4; ++i)
      inv[i] = 1.f / __shfl(rs[mq], lg * 4 + i);
#pragma unroll
    for (int dn = 0; dn < 4; ++dn) {
#pragma unroll
      for (int i = 0; i < 4; ++i) {
        const int q = qb * 128 + qrow + mq * 16 + lg * 4 + i;
        attnb[((size_t)(b * Ll + q)) * Dm + h * 64 + dn * 16 + l15] =
            __float2bfloat16(o[mq][dn][i] * inv[i]);
      }
    }
  }
}

// ---------------- LayerNorm: bf16 in, bf16 out (one row per block) ----------
__global__ __launch_bounds__(256) void k_ln(const bf16* __restrict__ x,
    const float* __restrict__ gamma, const float* __restrict__ beta,
    bf16* __restrict__ y)
{
  const size_t row = blockIdx.x;
  const int d0 = threadIdx.x * 4;
  const s16x4 xv = *(const s16x4*)((const short*)x + row * Dm + d0);
  float f0 = b2f(xv[0]), f1 = b2f(xv[1]), f2 = b2f(xv[2]), f3 = b2f(xv[3]);
  float s  = (f0 + f1) + (f2 + f3);
  float ss = (f0 * f0 + f1 * f1) + (f2 * f2 + f3 * f3);
#pragma unroll
  for (int m = 1; m < 64; m <<= 1) { s += __shfl_xor(s, m); ss += __shfl_xor(ss, m); }
  __shared__ float red[8];
  const int wv = threadIdx.x >> 6;
  if ((threadIdx.x & 63) == 0) { red[wv] = s; red[4 + wv] = ss; }
  __syncthreads();
  s  = red[0] + red[1] + red[2] + red[3];
  ss = red[4] + red[5] + red[6] + red[7];
  const float mu = s * (1.f / Dm);
  const float rstd = rsqrtf(ss * (1.f / Dm) - mu * mu + LNEPS);
  const float4 g  = *(const float4*)&gamma[d0];
  const float4 be = *(const float4*)&beta[d0];
  s16x4 o;
  o[0] = f2bs((f0 - mu) * rstd * g.x + be.x);
  o[1] = f2bs((f1 - mu) * rstd * g.y + be.y);
  o[2] = f2bs((f2 - mu) * rstd * g.z + be.z);
  o[3] = f2bs((f3 - mu) * rstd * g.w + be.w);
  *(s16x4*)((short*)y + row * Dm + d0) = o;
}

// ---------------- mean pool (bf16 in) ----------------
__global__ __launch_bounds__(256) void k_pool_part(const bf16* __restrict__ h3, float* __restrict__ part)
{
  const int b = blockIdx.x, lcn = blockIdx.y, dz = blockIdx.z;
  const int d = dz * 256 + threadIdx.x;
  float s = 0.f;
#pragma unroll 4
  for (int l = 0; l < 64; ++l)
    s += b2f(((const short*)h3)[((size_t)(b * Ll + lcn * 64 + l)) * Dm + d]);
  part[((size_t)(b * 16 + lcn)) * Dm + d] = s;
}

__global__ __launch_bounds__(256) void k_pool_fin(const float* __restrict__ part, float* __restrict__ out)
{
  const int b = blockIdx.x;
  const int d = blockIdx.y * 256 + threadIdx.x;
  float s = 0.f;
#pragma unroll
  for (int c = 0; c < 16; ++c) s += part[((size_t)(b * 16 + c)) * Dm + d];
  out[b * Dm + d] = s * (1.f / Ll);
  out[(size_t)Mm + b * Dm + d] = 1.f / Ll;  // attn_tokens == 1/L analytically
}

extern "C" void kernel_launch(void* const* d_in, const int* in_sizes, int n_in,
                              void* d_out, int out_size, void* d_ws, size_t ws_size,
                              hipStream_t stream) {
  const int*   tids  = (const int*)  d_in[0];
  const float* vals  = (const float*)d_in[1];
  const float* dels  = (const float*)d_in[2];
  const float* temb  = (const float*)d_in[3];
  const float* Wv    = (const float*)d_in[4];
  const float* bv    = (const float*)d_in[5];
  const float* Wt    = (const float*)d_in[6];
  const float* bt    = (const float*)d_in[7];
  const float* Win   = (const float*)d_in[8];
  const float* bin   = (const float*)d_in[9];
  const float* Wout  = (const float*)d_in[10];
  const float* bout  = (const float*)d_in[11];
  const float* W1    = (const float*)d_in[12];
  const float* b1    = (const float*)d_in[13];
  const float* W2    = (const float*)d_in[14];
  const float* b2    = (const float*)d_in[15];
  const float* gamma = (const float*)d_in[16];
  const float* beta  = (const float*)d_in[17];
  float* out = (float*)d_out;

  char* w = (char*)d_ws;
  const size_t MB = 1ull << 20;
  bf16*  hb    = (bf16*) (w + 0);         // [0,16)    h bf16 (QKV-A, Wout-res)
  bf16*  qkv   = (bf16*) (w + 16 * MB);   // [16,64)   q,k bf16 (V redirected)
  bf16*  vtb   = (bf16*) (w + 64 * MB);   // [64,80)   v^T (written by QKV gemm)
  bf16*  attnb = (bf16*) (w + 80 * MB);   // [80,96)   attn out (dead after Wout)
  bf16*  x1b   = (bf16*) (w + 16 * MB);   // [16,32)   h+attnout (qkv dead)
  bf16*  h2b   = (bf16*) (w + 32 * MB);   // [32,48)   LN1 out (FF1-A, FF2-res)
  bf16*  ff1   = (bf16*) (w + 48 * MB);   // [48,64)   relu(ff1)
  bf16*  x2b   = (bf16*) (w + 64 * MB);   // [64,80)   h2+ff2 (vtb dead)
  bf16*  h3b   = (bf16*) (w + 80 * MB);   // [80,96)   LN2 out (attnb dead)
  bf16*  WinB  = (bf16*) (w + 96 * MB);
  bf16*  WoutB = (bf16*) (w + 102 * MB);
  bf16*  W1B   = (bf16*) (w + 104 * MB);
  bf16*  W2B   = (bf16*) (w + 106 * MB);
  float* part  = (float*)(w + 108 * MB);

  k_prep<<<14336, 256, 0, stream>>>(Win, Wout, W1, W2, WinB, WoutB, W1B, W2B,
                                    tids, vals, dels, temb, Wv, bv, Wt, bt, hb);

  k_gemm8<false, false, true, true><<<dim3(64, 12), 512, 0, stream>>>(
      hb, WinB, bin, nullptr, qkv, vtb, 3072, 1024);

  k_attn<<<dim3(128, 8), 256, 0, stream>>>(qkv, vtb, attnb);

  k_gemm8<false, true, false, false><<<dim3(64, 4), 512, 0, stream>>>(
      attnb, WoutB, bout, hb, x1b, nullptr, 1024, 1024);

  k_ln<<<Mm, 256, 0, stream>>>(x1b, gamma, beta, h2b);

  k_gemm8<true, false, false, false><<<dim3(64, 4), 512, 0, stream>>>(
      h2b, W1B, b1, nullptr, ff1, nullptr, 1024, 1024);

  k_gemm8<false, true, false, false><<<dim3(64, 4), 512, 0, stream>>>(
      ff1, W2B, b2, h2b, x2b, nullptr, 1024, 1024);

  k_ln<<<Mm, 256, 0, stream>>>(x2b, gamma, beta, h3b);

  k_pool_part<<<dim3(8, 16, 4), 256, 0, stream>>>(h3b, part);
  k_pool_fin<<<dim3(8, 4), 256, 0, stream>>>(part, out);
}